// Round 6
// baseline (395.249 us; speedup 1.0000x reference)
//
#include <hip/hip_runtime.h>

// SteerableKernel: rotate [O,I,9,9] fp32 weights by G=8 angles via bilinear
// grid_sample (zeros padding, align_corners=False).
// Output: out[g][o][i][y][x], flat (g*C + c)*81 + p, c=o*I+i, p=y*9+x.
//
// KS=9, G=8 compile-time -> full 8x81 tap table is constexpr.
//   * g in {0,2,4,6}: EXACT grid permutations -> LDS gather (g0: pure copy).
//   * g in {1,3,5,7}: bilinear with compile-time taps + literal weights on a
//     register-held channel.
// ONE g PER BLOCK: grid = (C/64, 8). Input tile re-reads (8x) are L2/L3 hits
// (42.5 MB input vs 256 MB L3). LDS = lin + one out-tile = 41.5 KB ->
// 3 blocks/CU (was 2), 16384 fine-grained blocks -> store pipe continuously
// fed instead of 8 lock-stepped phases.
// All output stores are NONTEMPORAL (clang ext_vector float4 -> the builtin
// accepts it; HIP_vector_type float4 does not) -> no L2 write-allocate/RFO,
// same streaming path the 6.3 TB/s fill kernel uses.
// Barriers are raw lgkmcnt(0)+s_barrier (no vmcnt drain).

#define KS    9
#define NPIX  81
#define NC    64
#define BLOCK 256
#define NSLOT ((NC * NPIX) / 4)   // 1296 float4 slots per 64-channel tile

typedef float f4 __attribute__((ext_vector_type(4)));

// ---------------- compile-time tap table ----------------
struct Tap { int qA, qB; float w0, w1, w2, w3; };

constexpr double SQ2H = 0.70710678118654752440084436210485;
constexpr double CS[8] = {1.0,  SQ2H, 0.0, -SQ2H, -1.0, -SQ2H,  0.0,  SQ2H};
constexpr double SN[8] = {0.0,  SQ2H, 1.0,  SQ2H,  0.0, -SQ2H, -1.0, -SQ2H};

constexpr int cfloor(double v) { int i = (int)v; return (v < (double)i) ? i - 1 : i; }

constexpr Tap mk(int g, int p) {
    int py = p / KS, px = p - KS * py;
    double lx = ((double)px + 0.5) * (2.0 / KS) - 1.0;
    double ly = ((double)py + 0.5) * (2.0 / KS) - 1.0;
    double gx = CS[g] * lx - SN[g] * ly;
    double gy = SN[g] * lx + CS[g] * ly;
    double ix = ((gx + 1.0) * KS - 1.0) * 0.5;
    double iy = ((gy + 1.0) * KS - 1.0) * 0.5;
    int x0 = cfloor(ix), y0 = cfloor(iy);
    double fx = ix - x0, fy = iy - y0;
    double wx0 = 1.0 - fx, wx1 = fx;
    double pw0 = 0.0, pw1 = 0.0; int xs = 0;
    if (x0 >= 0 && x0 < KS - 1)      { xs = x0;     pw0 = wx0; pw1 = wx1; }
    else if (x0 == KS - 1)           { xs = KS - 2; pw0 = 0.0; pw1 = wx0; }
    else if (x0 == -1)               { xs = 0;      pw0 = wx1; pw1 = 0.0; }
    int yA = y0, yB = y0 + 1;
    double wyA = (yA >= 0 && yA < KS) ? (1.0 - fy) : 0.0;
    double wyB = (yB >= 0 && yB < KS) ? fy : 0.0;
    int yAc = yA < 0 ? 0 : (yA > KS - 1 ? KS - 1 : yA);
    int yBc = yB < 0 ? 0 : (yB > KS - 1 ? KS - 1 : yB);
    return Tap{ yAc * KS + xs, yBc * KS + xs,
                (float)(wyA * pw0), (float)(wyA * pw1),
                (float)(wyB * pw0), (float)(wyB * pw1) };
}

struct TapTab { Tap t[8][NPIX]; };
constexpr TapTab build_tab() {
    TapTab T{};
    for (int g = 0; g < 8; ++g)
        for (int p = 0; p < NPIX; ++p) T.t[g][p] = mk(g, p);
    return T;
}
constexpr TapTab TT = build_tab();

// ---- LDS-only barrier: order LDS ops, keep global stores in flight ----
__device__ __forceinline__ void bar_lds() {
    __builtin_amdgcn_sched_barrier(0);
    asm volatile("s_waitcnt lgkmcnt(0)" ::: "memory");
    __builtin_amdgcn_s_barrier();
    __builtin_amdgcn_sched_barrier(0);
}

__device__ __forceinline__ void st_nt(f4* dst, f4 v) {
    __builtin_nontemporal_store(v, dst);
}

// ---- odd-g compute: compile-time taps & literal weights ----
template<int G, int P>
__device__ __forceinline__ void one_out(const float (&r)[NPIX], float* otrow) {
    constexpr Tap t = TT.t[G][P];
    float v = 0.0f;
    if constexpr (t.w0 != 0.0f) v += r[t.qA]     * t.w0;
    if constexpr (t.w1 != 0.0f) v += r[t.qA + 1] * t.w1;
    if constexpr (t.w2 != 0.0f) v += r[t.qB]     * t.w2;
    if constexpr (t.w3 != 0.0f) v += r[t.qB + 1] * t.w3;
    otrow[P] = v;                       // ds_write_b32 offset:P*4
}

template<int G, int P0, int NP>
__device__ __forceinline__ void compute_range(const float (&r)[NPIX], float* otrow) {
    if constexpr (NP > 0) {
        one_out<G, P0>(r, otrow);
        compute_range<G, P0 + 1, NP - 1>(r, otrow);
    }
}

template<int G>
__device__ __forceinline__ void compute_quarter(int gq, const float (&r)[NPIX],
                                                float* otrow) {
    // gq = t>>6 is wave-uniform -> no divergence.
    if (gq == 0)      compute_range<G,  0, 20>(r, otrow);
    else if (gq == 1) compute_range<G, 20, 20>(r, otrow);
    else if (gq == 2) compute_range<G, 40, 20>(r, otrow);
    else              compute_range<G, 60, 21>(r, otrow);
}

// ---- even-g: exact permutation gather ----
__device__ __forceinline__ void cp_of(int d, int& c, int& p) {
    c = (d * 6473) >> 19;               // floor(d/81), valid for d < 20971
    p = d - NPIX * c;
}

template<int G>
__device__ __forceinline__ int qe(int p) {
    if constexpr (G == 0) return p;
    else if constexpr (G == 4) return 80 - p;
    else {
        int py = (p * 57) >> 9;         // floor(p/9), valid for p < 512
        int px = p - KS * py;
        if constexpr (G == 2) return KS * px + 8 - py;   // 90 deg
        else                  return 72 - KS * px + py;  // 270 deg
    }
}

template<int G>
__device__ __forceinline__ void do_even(const float* lin, f4* d4, int t) {
    if constexpr (G == 0) {             // identity: straight float4 copy
        const f4* s4 = (const f4*)lin;
        for (int j = t; j < NSLOT; j += BLOCK) st_nt(&d4[j], s4[j]);
    } else {
        for (int j = t; j < NSLOT; j += BLOCK) {
            int d0 = 4 * j;
            f4 v;
#pragma unroll
            for (int k = 0; k < 4; ++k) {   // slots can straddle channel rows
                int c, p; cp_of(d0 + k, c, p);
                v[k] = lin[c * NPIX + qe<G>(p)];
            }
            st_nt(&d4[j], v);
        }
    }
}

template<int G>
__device__ __forceinline__ void do_odd(const float* lin, float* ot,
                                       f4* d4, int t) {
    const int c = t & 63, gq = t >> 6;
    // Own channel -> registers (81 x ds_read_b32, immediate offsets;
    // lanes hit distinct banks: stride 81 dwords, gcd(81,32)=1).
    float r[NPIX];
    const float* myrow = &lin[c * NPIX];
#pragma unroll
    for (int j = 0; j < NPIX; ++j) r[j] = myrow[j];
    compute_quarter<G>(gq, r, &ot[c * NPIX]);
    bar_lds();
    const f4* s4 = (const f4*)ot;
    for (int j = t; j < NSLOT; j += BLOCK) st_nt(&d4[j], s4[j]);
}

__global__ __launch_bounds__(BLOCK) void st_rotate(
        const float* __restrict__ in, float* __restrict__ out, int C) {
    __shared__ __align__(16) float lin[NC * NPIX];    // 20736 B input tile
    __shared__ __align__(16) float ot[NC * NPIX];     // 20736 B out tile (odd g)
    const int t = threadIdx.x;
    const int g = blockIdx.y;
    const int c0 = blockIdx.x * NC;

    // Stage 64 channels, coalesced float4 (8x re-reads hit L2/L3).
    {
        const f4* src = (const f4*)(in + (size_t)c0 * NPIX);
        f4* dst = (f4*)lin;
        for (int j = t; j < NSLOT; j += BLOCK) dst[j] = src[j];
    }
    bar_lds();

    f4* d4 = (f4*)(out + ((size_t)g * C + c0) * NPIX);
    switch (g) {                        // block-uniform, no divergence
        case 0: do_even<0>(lin, d4, t); break;
        case 1: do_odd <1>(lin, ot, d4, t); break;
        case 2: do_even<2>(lin, d4, t); break;
        case 3: do_odd <3>(lin, ot, d4, t); break;
        case 4: do_even<4>(lin, d4, t); break;
        case 5: do_odd <5>(lin, ot, d4, t); break;
        case 6: do_even<6>(lin, d4, t); break;
        default: do_odd<7>(lin, ot, d4, t); break;
    }
    // outstanding nt stores drain at s_endpgm.
}

extern "C" void kernel_launch(void* const* d_in, const int* in_sizes, int n_in,
                              void* d_out, int out_size, void* d_ws, size_t ws_size,
                              hipStream_t stream) {
    const float* in = (const float*)d_in[0];
    float* out = (float*)d_out;
    const int C = in_sizes[0] / NPIX;          // 131072 channels (O*I)
    // G fixed at 8 by the compile-time table; out_size/in_sizes[0] == 8.
    dim3 grid(C / NC, 8, 1);
    st_rotate<<<grid, BLOCK, 0, stream>>>(in, out, C);
}

// Round 7
// 365.795 us; speedup vs baseline: 1.0805x; 1.0805x over previous
//
#include <hip/hip_runtime.h>

// SteerableKernel: rotate [O,I,9,9] fp32 weights by G=8 angles via bilinear
// grid_sample (zeros padding, align_corners=False).
// Output: out[g][o][i][y][x], flat (g*C + c)*81 + p, c=o*I+i, p=y*9+x.
//
// KS=9, G=8 compile-time -> full 8x81 tap table is constexpr.
//   * g in {0,2,4,6}: EXACT grid permutations -> gather straight from the
//     LDS input tile -> coalesced float4 stores, front-loaded right after
//     the stage barrier so the store queue fills immediately.
//   * g in {1,3,5,7}: bilinear taps read DIRECTLY from lin at compile-time
//     immediate dword offsets (ds_read2_b32 pairs; lane stride 81 dwords,
//     gcd(81,32)=1 -> conflict-free). No r[81] register copy: kills the
//     81-deep serial load head and ~90 VGPRs.
// LDS = lin + ONE out-tile = 41472 B -> 3 blocks/CU (R4 had 62 KB -> 2).
// Barriers: raw lgkmcnt(0)+s_barrier only (no vmcnt drain) — global stores
// stay in flight across all 8 phases and drain at endpgm.

#define KS    9
#define NPIX  81
#define NC    64
#define BLOCK 256
#define NSLOT ((NC * NPIX) / 4)   // 1296 float4 slots per 64-channel tile

typedef float f4 __attribute__((ext_vector_type(4)));

// ---------------- compile-time tap table ----------------
struct Tap { int qA, qB; float w0, w1, w2, w3; };

constexpr double SQ2H = 0.70710678118654752440084436210485;
constexpr double CS[8] = {1.0,  SQ2H, 0.0, -SQ2H, -1.0, -SQ2H,  0.0,  SQ2H};
constexpr double SN[8] = {0.0,  SQ2H, 1.0,  SQ2H,  0.0, -SQ2H, -1.0, -SQ2H};

constexpr int cfloor(double v) { int i = (int)v; return (v < (double)i) ? i - 1 : i; }

constexpr Tap mk(int g, int p) {
    int py = p / KS, px = p - KS * py;
    double lx = ((double)px + 0.5) * (2.0 / KS) - 1.0;
    double ly = ((double)py + 0.5) * (2.0 / KS) - 1.0;
    double gx = CS[g] * lx - SN[g] * ly;
    double gy = SN[g] * lx + CS[g] * ly;
    double ix = ((gx + 1.0) * KS - 1.0) * 0.5;
    double iy = ((gy + 1.0) * KS - 1.0) * 0.5;
    int x0 = cfloor(ix), y0 = cfloor(iy);
    double fx = ix - x0, fy = iy - y0;
    double wx0 = 1.0 - fx, wx1 = fx;
    double pw0 = 0.0, pw1 = 0.0; int xs = 0;
    if (x0 >= 0 && x0 < KS - 1)      { xs = x0;     pw0 = wx0; pw1 = wx1; }
    else if (x0 == KS - 1)           { xs = KS - 2; pw0 = 0.0; pw1 = wx0; }
    else if (x0 == -1)               { xs = 0;      pw0 = wx1; pw1 = 0.0; }
    int yA = y0, yB = y0 + 1;
    double wyA = (yA >= 0 && yA < KS) ? (1.0 - fy) : 0.0;
    double wyB = (yB >= 0 && yB < KS) ? fy : 0.0;
    int yAc = yA < 0 ? 0 : (yA > KS - 1 ? KS - 1 : yA);
    int yBc = yB < 0 ? 0 : (yB > KS - 1 ? KS - 1 : yB);
    return Tap{ yAc * KS + xs, yBc * KS + xs,
                (float)(wyA * pw0), (float)(wyA * pw1),
                (float)(wyB * pw0), (float)(wyB * pw1) };
}

struct TapTab { Tap t[8][NPIX]; };
constexpr TapTab build_tab() {
    TapTab T{};
    for (int g = 0; g < 8; ++g)
        for (int p = 0; p < NPIX; ++p) T.t[g][p] = mk(g, p);
    return T;
}
constexpr TapTab TT = build_tab();

// ---- LDS-only barrier: order LDS ops, keep global stores in flight ----
__device__ __forceinline__ void bar_lds() {
    __builtin_amdgcn_sched_barrier(0);
    asm volatile("s_waitcnt lgkmcnt(0)" ::: "memory");
    __builtin_amdgcn_s_barrier();
    __builtin_amdgcn_sched_barrier(0);
}

// ---- odd-g compute: taps gathered from lin at immediate offsets ----
template<int G, int P>
__device__ __forceinline__ void one_out(const float* lrow, float* otrow) {
    constexpr Tap t = TT.t[G][P];
    float v = 0.0f;
    if constexpr (t.w0 != 0.0f) v += lrow[t.qA]     * t.w0;
    if constexpr (t.w1 != 0.0f) v += lrow[t.qA + 1] * t.w1;
    if constexpr (t.w2 != 0.0f) v += lrow[t.qB]     * t.w2;
    if constexpr (t.w3 != 0.0f) v += lrow[t.qB + 1] * t.w3;
    otrow[P] = v;                       // ds_write_b32 offset:P*4
}

template<int G, int P0, int NP>
__device__ __forceinline__ void compute_range(const float* lrow, float* otrow) {
    if constexpr (NP > 0) {
        one_out<G, P0>(lrow, otrow);
        compute_range<G, P0 + 1, NP - 1>(lrow, otrow);
    }
}

template<int G>
__device__ __forceinline__ void compute_quarter(int gq, const float* lrow,
                                                float* otrow) {
    // gq = t>>6 is wave-uniform -> no divergence.
    if (gq == 0)      compute_range<G,  0, 20>(lrow, otrow);
    else if (gq == 1) compute_range<G, 20, 20>(lrow, otrow);
    else if (gq == 2) compute_range<G, 40, 20>(lrow, otrow);
    else              compute_range<G, 60, 21>(lrow, otrow);
}

// ---- even-g: exact permutation gather ----
__device__ __forceinline__ void cp_of(int d, int& c, int& p) {
    c = (d * 6473) >> 19;               // floor(d/81), valid for d < 20971
    p = d - NPIX * c;
}

template<int G>
__device__ __forceinline__ int qe(int p) {
    if constexpr (G == 0) return p;
    else if constexpr (G == 4) return 80 - p;
    else {
        int py = (p * 57) >> 9;         // floor(p/9), valid for p < 512
        int px = p - KS * py;
        if constexpr (G == 2) return KS * px + 8 - py;   // 90 deg
        else                  return 72 - KS * px + py;  // 270 deg
    }
}

template<int G>
__device__ __forceinline__ void do_even(const float* lin, f4* d4, int t) {
    if constexpr (G == 0) {             // identity: straight float4 copy
        const f4* s4 = (const f4*)lin;
        for (int j = t; j < NSLOT; j += BLOCK) d4[j] = s4[j];
    } else {
        for (int j = t; j < NSLOT; j += BLOCK) {
            int d0 = 4 * j;
            f4 v;
#pragma unroll
            for (int k = 0; k < 4; ++k) {   // slots can straddle channel rows
                int c, p; cp_of(d0 + k, c, p);
                v[k] = lin[c * NPIX + qe<G>(p)];
            }
            d4[j] = v;
        }
    }
}

__device__ __forceinline__ void flush_ot(const float* ot, f4* d4, int t) {
    const f4* s4 = (const f4*)ot;
    for (int j = t; j < NSLOT; j += BLOCK) d4[j] = s4[j];
}

__global__ __launch_bounds__(BLOCK) void st_rotate(
        const float* __restrict__ in, float* __restrict__ out, int C) {
    __shared__ __align__(16) float lin[NC * NPIX];    // 20736 B input tile
    __shared__ __align__(16) float ot[NC * NPIX];     // 20736 B out tile
    const int t = threadIdx.x;
    const int c0 = blockIdx.x * NC;

    // Stage 64 channels, coalesced float4 (c0*81 dwords % 4 == 0).
    {
        const f4* src = (const f4*)(in + (size_t)c0 * NPIX);
        f4* dst = (f4*)lin;
        for (int j = t; j < NSLOT; j += BLOCK) dst[j] = src[j];
    }
    bar_lds();

    f4* const ob = (f4*)(out + (size_t)c0 * NPIX);    // g=0 tile base
    const size_t gs4 = (size_t)C * NPIX / 4;          // g stride in float4

    // Front-load all even-g flushes: store queue fills immediately and
    // drains under the odd-g compute phases.
    do_even<0>(lin, ob + 0 * gs4, t);
    do_even<2>(lin, ob + 2 * gs4, t);
    do_even<4>(lin, ob + 4 * gs4, t);
    do_even<6>(lin, ob + 6 * gs4, t);

    const int c = t & 63, gq = t >> 6;
    const float* lrow = &lin[c * NPIX];
    float* otrow = &ot[c * NPIX];

    // Odd g's: compute -> bar -> flush -> bar (single out-tile).
    compute_quarter<1>(gq, lrow, otrow);
    bar_lds();
    flush_ot(ot, ob + 1 * gs4, t);
    bar_lds();
    compute_quarter<3>(gq, lrow, otrow);
    bar_lds();
    flush_ot(ot, ob + 3 * gs4, t);
    bar_lds();
    compute_quarter<5>(gq, lrow, otrow);
    bar_lds();
    flush_ot(ot, ob + 5 * gs4, t);
    bar_lds();
    compute_quarter<7>(gq, lrow, otrow);
    bar_lds();
    flush_ot(ot, ob + 7 * gs4, t);
    // outstanding stores drain at s_endpgm.
}

extern "C" void kernel_launch(void* const* d_in, const int* in_sizes, int n_in,
                              void* d_out, int out_size, void* d_ws, size_t ws_size,
                              hipStream_t stream) {
    const float* in = (const float*)d_in[0];
    float* out = (float*)d_out;
    const int C = in_sizes[0] / NPIX;          // 131072 channels (O*I)
    // G fixed at 8 by the compile-time table; out_size/in_sizes[0] == 8.
    st_rotate<<<C / NC, BLOCK, 0, stream>>>(in, out, C);
}